// Round 1
// baseline (1099.734 us; speedup 1.0000x reference)
//
#include <hip/hip_runtime.h>
#include <cmath>
#include <cstdint>

#define NPOS 49
#define NANCH 588

// ---------------------------------------------------------------------------
// Weight transposes: w[O][CK] -> wt[CK][O]  (coalesced loads in conv kernels)
// w1 gets a float4-interleaved layout: w1q[cq*256 + o] = {w[o][4cq..4cq+3]}
// ---------------------------------------------------------------------------
__global__ void transpose_all(
    const float* __restrict__ w1, const float* __restrict__ w2,
    const float* __restrict__ w3, const float* __restrict__ w4,
    const float* __restrict__ wb, const float* __restrict__ wc,
    float* __restrict__ w1t, float* __restrict__ w2t, float* __restrict__ w3t,
    float* __restrict__ w4t, float* __restrict__ wbt, float* __restrict__ wct) {
  int idx = blockIdx.x * blockDim.x + threadIdx.x;
  if (idx < 131072) {  // w1 [256][512] -> interleaved-4: [(c/4)*256 + o][c%4]
    int o = idx / 512, c = idx % 512;
    w1t[((c >> 2) * 256 + o) * 4 + (c & 3)] = w1[idx];
    return;
  }
  idx -= 131072;
  if (idx < 589824) { int o = idx / 2304, ck = idx % 2304; w2t[ck * 256 + o] = w2[idx]; return; }
  idx -= 589824;
  if (idx < 589824) { int o = idx / 2304, ck = idx % 2304; w3t[ck * 256 + o] = w3[idx]; return; }
  idx -= 589824;
  if (idx < 589824) { int o = idx / 2304, ck = idx % 2304; w4t[ck * 256 + o] = w4[idx]; return; }
  idx -= 589824;
  if (idx < 110592) { int o = idx / 2304, ck = idx % 2304; wbt[ck * 48 + o] = wb[idx]; return; }
  idx -= 110592;
  if (idx < 27648)  { int o = idx / 2304, ck = idx % 2304; wct[ck * 12 + o] = wc[idx]; return; }
}

// ---------------------------------------------------------------------------
// conv 1x1 (512 -> 256) + bias + BN + ReLU.  One block per image, 512 thr.
// thread = out channel (t&255), c-split 2-way (t>>8), LDS reduce.
// ---------------------------------------------------------------------------
__global__ __launch_bounds__(512, 2) void conv1x1_bn(
    const float* __restrict__ in, const float* __restrict__ w1q,
    const float* __restrict__ bias, const float* __restrict__ gg,
    const float* __restrict__ be, const float* __restrict__ mu,
    const float* __restrict__ var, float* __restrict__ out) {
  __shared__ float smem[512 * 52];  // tile [512][52] (pad for b128 align); reused as partial [256][49]
  const int b = blockIdx.x, t = threadIdx.x;
  const float* inb = in + (size_t)b * (512 * NPOS);
  for (int i = t; i < 512 * NPOS; i += 512) {
    int c = i / NPOS, p = i - c * NPOS;
    smem[c * 52 + p] = inb[i];
  }
  __syncthreads();
  const int o = t & 255, cg = t >> 8;
  float acc[NPOS];
#pragma unroll
  for (int p = 0; p < NPOS; ++p) acc[p] = 0.f;
  const float4* wq = (const float4*)w1q;
  const int cq0 = cg * 64;               // 64 groups of 4 input channels
  float4 wcur = wq[cq0 * 256 + o];
  for (int cq = cq0; cq < cq0 + 64; ++cq) {
    int nq = (cq + 1 < cq0 + 64) ? cq + 1 : cq;
    float4 wnext = wq[nq * 256 + o];     // prefetch
    const float* tb = smem + (cq * 4) * 52;
#pragma unroll
    for (int j = 0; j < 4; ++j) {
      float w = (j == 0) ? wcur.x : (j == 1) ? wcur.y : (j == 2) ? wcur.z : wcur.w;
      const float* tr = tb + j * 52;
#pragma unroll
      for (int p = 0; p < NPOS; ++p) acc[p] = fmaf(w, tr[p], acc[p]);
    }
    wcur = wnext;
  }
  __syncthreads();
  float* part = smem;
  if (cg == 1) {
#pragma unroll
    for (int p = 0; p < NPOS; ++p) part[o * NPOS + p] = acc[p];
  }
  __syncthreads();
  if (cg == 0) {
    float scale = gg[o] / sqrtf(var[o] + 1e-5f);
    float add = (bias[o] - mu[o]) * scale + be[o];
#pragma unroll
    for (int p = 0; p < NPOS; ++p) {
      float v = acc[p] + part[o * NPOS + p];
      v = v * scale + add;
      part[o * NPOS + p] = v > 0.f ? v : 0.f;
    }
  }
  __syncthreads();
  float* outb = out + (size_t)b * (256 * NPOS);
  for (int i = t; i < 256 * NPOS; i += 512) outb[i] = part[i];
}

// ---------------------------------------------------------------------------
// conv 3x3 pad1 (256 -> 256) + bias + BN + ReLU.  One block per image, 512 thr.
// LDS tile padded [256][9][12] (zero borders); weights [ck][256] coalesced,
// prefetched one c ahead.
// ---------------------------------------------------------------------------
__global__ __launch_bounds__(512, 2) void conv3x3_bn(
    const float* __restrict__ in, const float* __restrict__ wt,
    const float* __restrict__ bias, const float* __restrict__ gg,
    const float* __restrict__ be, const float* __restrict__ mu,
    const float* __restrict__ var, float* __restrict__ out) {
  __shared__ float smem[256 * 108];  // [c][9][12], 110,592 B
  const int b = blockIdx.x, t = threadIdx.x;
  for (int i = t; i < 256 * 108; i += 512) smem[i] = 0.f;
  __syncthreads();
  const float* inb = in + (size_t)b * (256 * NPOS);
  for (int i = t; i < 256 * NPOS; i += 512) {
    int c = i / NPOS, p = i - c * NPOS, y = p / 7, x = p - y * 7;
    smem[c * 108 + (y + 1) * 12 + (x + 1)] = inb[i];
  }
  __syncthreads();
  const int o = t & 255, cg = t >> 8;
  float acc[NPOS];
#pragma unroll
  for (int p = 0; p < NPOS; ++p) acc[p] = 0.f;
  const int c0 = cg * 128;
  float wc_[9], wn_[9];
#pragma unroll
  for (int k = 0; k < 9; ++k) wc_[k] = wt[(c0 * 9 + k) * 256 + o];
  for (int c = c0; c < c0 + 128; ++c) {
    int cn = (c + 1 < c0 + 128) ? c + 1 : c;
#pragma unroll
    for (int k = 0; k < 9; ++k) wn_[k] = wt[(cn * 9 + k) * 256 + o];  // prefetch
    const float* tb = smem + c * 108;
#pragma unroll
    for (int y = 0; y < 7; ++y) {
#pragma unroll
      for (int ky = 0; ky < 3; ++ky) {
        const float* row = tb + (y + ky) * 12;
#pragma unroll
        for (int x = 0; x < 7; ++x) {
#pragma unroll
          for (int kx = 0; kx < 3; ++kx)
            acc[y * 7 + x] = fmaf(wc_[ky * 3 + kx], row[x + kx], acc[y * 7 + x]);
        }
      }
    }
#pragma unroll
    for (int k = 0; k < 9; ++k) wc_[k] = wn_[k];
  }
  __syncthreads();
  float* part = smem;
  if (cg == 1) {
#pragma unroll
    for (int p = 0; p < NPOS; ++p) part[o * NPOS + p] = acc[p];
  }
  __syncthreads();
  if (cg == 0) {
    float scale = gg[o] / sqrtf(var[o] + 1e-5f);
    float add = (bias[o] - mu[o]) * scale + be[o];
#pragma unroll
    for (int p = 0; p < NPOS; ++p) {
      float v = acc[p] + part[o * NPOS + p];
      v = v * scale + add;
      part[o * NPOS + p] = v > 0.f ? v : 0.f;
    }
  }
  __syncthreads();
  float* outb = out + (size_t)b * (256 * NPOS);
  for (int i = t; i < 256 * NPOS; i += 512) outb[i] = part[i];
}

// ---------------------------------------------------------------------------
// Heads (box 48ch + cls 12ch, 3x3 pad1) + decode + sigmoid + stable sort +
// greedy NMS + top-100 write.  One block per image, 256 threads.
// ---------------------------------------------------------------------------
__global__ __launch_bounds__(256, 1) void heads_nms(
    const float* __restrict__ in, const float* __restrict__ wbt,
    const float* __restrict__ wct, const float* __restrict__ bb,
    const float* __restrict__ bc, float* __restrict__ out) {
  __shared__ float smem[27648];  // 110,592 B, phase-reused
  const int b = blockIdx.x, t = threadIdx.x;
  // ---- phase A: head convs ----
  for (int i = t; i < 256 * 108; i += 256) smem[i] = 0.f;
  __syncthreads();
  const float* inb = in + (size_t)b * (256 * NPOS);
  for (int i = t; i < 256 * NPOS; i += 256) {
    int c = i / NPOS, p = i - c * NPOS, y = p / 7, x = p - y * 7;
    smem[c * 108 + (y + 1) * 12 + (x + 1)] = inb[i];
  }
  __syncthreads();
  float acc[NPOS];
#pragma unroll
  for (int p = 0; p < NPOS; ++p) acc[p] = 0.f;
  int o = 0, cg = 0;
  if (t < 240) {
    o = t % 60; cg = t / 60;  // 60 out channels x 4-way c-split (64 each)
    const float* wbase; int wstr;
    if (o < 48) { wbase = wbt + o; wstr = 48; }
    else        { wbase = wct + (o - 48); wstr = 12; }
    const int c0 = cg * 64;
    float wc_[9], wn_[9];
#pragma unroll
    for (int k = 0; k < 9; ++k) wc_[k] = wbase[(c0 * 9 + k) * wstr];
    for (int c = c0; c < c0 + 64; ++c) {
      int cn = (c + 1 < c0 + 64) ? c + 1 : c;
#pragma unroll
      for (int k = 0; k < 9; ++k) wn_[k] = wbase[(cn * 9 + k) * wstr];
      const float* tb = smem + c * 108;
#pragma unroll
      for (int y = 0; y < 7; ++y) {
#pragma unroll
        for (int ky = 0; ky < 3; ++ky) {
          const float* row = tb + (y + ky) * 12;
#pragma unroll
          for (int x = 0; x < 7; ++x) {
#pragma unroll
            for (int kx = 0; kx < 3; ++kx)
              acc[y * 7 + x] = fmaf(wc_[ky * 3 + kx], row[x + kx], acc[y * 7 + x]);
          }
        }
      }
#pragma unroll
      for (int k = 0; k < 9; ++k) wc_[k] = wn_[k];
    }
  }
  __syncthreads();
  float* P = smem;          // [3][60][49] = 8820 floats
  float* H = smem + 10240;  // [60][49]  head outputs (ch-major)
  if (t < 240 && cg > 0) {
#pragma unroll
    for (int p = 0; p < NPOS; ++p) P[((cg - 1) * 60 + o) * NPOS + p] = acc[p];
  }
  __syncthreads();
  if (t < 60) {  // cg == 0
    float bsum = (o < 48) ? bb[o] : bc[o - 48];
#pragma unroll
    for (int p = 0; p < NPOS; ++p)
      H[o * NPOS + p] = acc[p] + P[o * NPOS + p] + P[(60 + o) * NPOS + p] +
                        P[(120 + o) * NPOS + p] + bsum;
  }
  __syncthreads();
  // ---- phase B: decode + sigmoid ----
  float* BX = smem + 13440;  // [588][4]
  float* SC = smem + 15808;  // [588]
  const float scl[4] = {0.3f, 0.5f, 0.7f, 0.9f};
  const float rat[3] = {0.7f, 1.0f, 1.3f};
  for (int n = t; n < NANCH; n += 256) {
    int p = n / 12, a = n - p * 12;
    int ph = p / 7, pw = p - ph * 7;
    float cx = (ph + 0.5f) / 7.0f;
    float cy = (pw + 0.5f) / 7.0f;
    int s = a / 3, r = a - s * 3;
    float rt = sqrtf(rat[r]);
    float wsz = scl[s] * rt, hsz = scl[s] / rt;
    // replicate reference anchor arithmetic exactly
    float x1 = cx + (-wsz) * 0.5f, y1 = cy + (-hsz) * 0.5f;
    float x2 = cx + wsz * 0.5f,    y2 = cy + hsz * 0.5f;
    float acx = (x1 + x2) * 0.5f,  acy = (y1 + y2) * 0.5f;
    float asx = x2 - x1,           asy = y2 - y1;
    float bp0 = H[(a * 4 + 0) * NPOS + p];
    float bp1 = H[(a * 4 + 1) * NPOS + p];
    float bp2 = H[(a * 4 + 2) * NPOS + p];
    float bp3 = H[(a * 4 + 3) * NPOS + p];
    float pcx = bp0 * asx + acx;
    float pcy = bp1 * asy + acy;
    float psx = expf(bp2) * asx;
    float psy = expf(bp3) * asy;
    BX[n * 4 + 0] = pcx - psx * 0.5f;
    BX[n * 4 + 1] = pcy - psy * 0.5f;
    BX[n * 4 + 2] = pcx + psx * 0.5f;
    BX[n * 4 + 3] = pcy + psy * 0.5f;
    float lg = H[(48 + a) * NPOS + p];
    SC[n] = 1.0f / (1.0f + expf(-lg));
  }
  __syncthreads();
  // ---- phase C: stable bitonic sort (score desc, idx asc) ----
  uint64_t* KEY = (uint64_t*)(smem + 18176);  // 1024 keys
  for (int i = t; i < 1024; i += 256) {
    if (i < NANCH) {
      uint32_t u = __float_as_uint(SC[i]);
      u = (u & 0x80000000u) ? ~u : (u | 0x80000000u);  // monotonic map
      u = ~u;                                          // descending score
      KEY[i] = ((uint64_t)u << 32) | (uint32_t)i;
    } else {
      KEY[i] = ~0ULL;  // padding -> end
    }
  }
  __syncthreads();
  for (int k = 2; k <= 1024; k <<= 1) {
    for (int j = k >> 1; j > 0; j >>= 1) {
      for (int i = t; i < 1024; i += 256) {
        int ixj = i ^ j;
        if (ixj > i) {
          uint64_t a = KEY[i], b2 = KEY[ixj];
          bool up = ((i & k) == 0);
          if ((a > b2) == up) { KEY[i] = b2; KEY[ixj] = a; }
        }
      }
      __syncthreads();
    }
  }
  // ---- phase D: gather sorted boxes/scores ----
  float* SB  = smem + 20224;  // [588][4]
  float* SSc = smem + 22576;  // [588]
  for (int i = t; i < NANCH; i += 256) {
    int si = (int)(KEY[i] & 0xFFFFFFFFu);
    SB[i * 4 + 0] = BX[si * 4 + 0];
    SB[i * 4 + 1] = BX[si * 4 + 1];
    SB[i * 4 + 2] = BX[si * 4 + 2];
    SB[i * 4 + 3] = BX[si * 4 + 3];
    SSc[i] = SC[si];
  }
  __syncthreads();
  // ---- phase E: IoU adjacency bitmask (row-major over sorted order) ----
  uint64_t* ADJ = (uint64_t*)smem;  // [588][10] words, 47,040 B (P/H/BX dead)
  for (int i = t; i < NANCH; i += 256) {
    float ax1 = SB[i * 4 + 0], ay1 = SB[i * 4 + 1];
    float ax2 = SB[i * 4 + 2], ay2 = SB[i * 4 + 3];
    float aar = (ax2 - ax1) * (ay2 - ay1);
    for (int w = 0; w < 10; ++w) {
      uint64_t bits = 0;
      int jbase = w * 64;
      int jend = NANCH - jbase; if (jend > 64) jend = 64;
      for (int bi = 0; bi < jend; ++bi) {
        int j = jbase + bi;
        float bx1 = SB[j * 4 + 0], by1 = SB[j * 4 + 1];
        float bx2 = SB[j * 4 + 2], by2 = SB[j * 4 + 3];
        float bar = (bx2 - bx1) * (by2 - by1);
        float ltx = fmaxf(ax1, bx1), lty = fmaxf(ay1, by1);
        float rbx = fminf(ax2, bx2), rby = fminf(ay2, by2);
        float wx = rbx - ltx; wx = wx > 0.f ? wx : 0.f;
        float wy = rby - lty; wy = wy > 0.f ? wy : 0.f;
        float inter = wx * wy;
        float iou = inter / (aar + bar - inter + 1e-9f);
        if (iou > 0.5f) bits |= (1ULL << bi);
      }
      ADJ[i * 10 + w] = bits;
    }
  }
  __syncthreads();
  // ---- phase F: serial greedy suppression scan + write ----
  float* OUTB = smem + 23168;  // [100][6]
  for (int i = t; i < 600; i += 256) OUTB[i] = 0.f;
  __syncthreads();
  if (t == 0) {
    uint64_t supp[10];
#pragma unroll
    for (int w = 0; w < 10; ++w) supp[w] = 0;
    int cnt = 0;
    for (int i = 0; i < NANCH && cnt < 100; ++i) {
      bool sup = (supp[i >> 6] >> (i & 63)) & 1ULL;
      if (!sup && SSc[i] > 0.3f) {
        OUTB[cnt * 6 + 0] = SB[i * 4 + 0];
        OUTB[cnt * 6 + 1] = SB[i * 4 + 1];
        OUTB[cnt * 6 + 2] = SB[i * 4 + 2];
        OUTB[cnt * 6 + 3] = SB[i * 4 + 3];
        OUTB[cnt * 6 + 4] = SSc[i];
        OUTB[cnt * 6 + 5] = 1.0f;
        ++cnt;
        int iw = i >> 6;
        uint64_t himask = ~((2ULL << (i & 63)) - 1ULL);  // bits > (i&63)
#pragma unroll
        for (int w = 0; w < 10; ++w) {
          uint64_t m = ADJ[i * 10 + w];
          if (w < iw) m = 0;
          else if (w == iw) m &= himask;
          supp[w] |= m;
        }
      }
    }
  }
  __syncthreads();
  float* ob = out + (size_t)b * 600;
  for (int i = t; i < 600; i += 256) ob[i] = OUTB[i];
}

// ---------------------------------------------------------------------------
extern "C" void kernel_launch(void* const* d_in, const int* in_sizes, int n_in,
                              void* d_out, int out_size, void* d_ws, size_t ws_size,
                              hipStream_t stream) {
  const float* feat = (const float*)d_in[0];
  const float* w1  = (const float*)d_in[1];
  const float* b1  = (const float*)d_in[2];
  const float* g1  = (const float*)d_in[3];
  const float* be1 = (const float*)d_in[4];
  const float* mu1 = (const float*)d_in[5];
  const float* v1  = (const float*)d_in[6];
  const float* w2  = (const float*)d_in[7];
  const float* b2  = (const float*)d_in[8];
  const float* g2  = (const float*)d_in[9];
  const float* be2 = (const float*)d_in[10];
  const float* mu2 = (const float*)d_in[11];
  const float* v2  = (const float*)d_in[12];
  const float* w3  = (const float*)d_in[13];
  const float* b3  = (const float*)d_in[14];
  const float* g3  = (const float*)d_in[15];
  const float* be3 = (const float*)d_in[16];
  const float* mu3 = (const float*)d_in[17];
  const float* v3  = (const float*)d_in[18];
  const float* w4  = (const float*)d_in[19];
  const float* b4  = (const float*)d_in[20];
  const float* g4  = (const float*)d_in[21];
  const float* be4 = (const float*)d_in[22];
  const float* mu4 = (const float*)d_in[23];
  const float* v4  = (const float*)d_in[24];
  const float* wcls = (const float*)d_in[25];
  const float* bcls = (const float*)d_in[26];
  const float* wbox = (const float*)d_in[27];
  const float* bbox = (const float*)d_in[28];

  const int B = in_sizes[0] / (512 * NPOS);
  float* ws  = (float*)d_ws;
  size_t xsz = (size_t)B * 256 * NPOS;
  float* xa  = ws;
  float* xb  = xa + xsz;
  float* w1t = xb + xsz;
  float* w2t = w1t + 131072;
  float* w3t = w2t + 589824;
  float* w4t = w3t + 589824;
  float* wbt = w4t + 589824;
  float* wct = wbt + 110592;

  transpose_all<<<(2038784 + 255) / 256, 256, 0, stream>>>(
      w1, w2, w3, w4, wbox, wcls, w1t, w2t, w3t, w4t, wbt, wct);
  conv1x1_bn<<<B, 512, 0, stream>>>(feat, w1t, b1, g1, be1, mu1, v1, xa);
  conv3x3_bn<<<B, 512, 0, stream>>>(xa, w2t, b2, g2, be2, mu2, v2, xb);
  conv3x3_bn<<<B, 512, 0, stream>>>(xb, w3t, b3, g3, be3, mu3, v3, xa);
  conv3x3_bn<<<B, 512, 0, stream>>>(xa, w4t, b4, g4, be4, mu4, v4, xb);
  heads_nms<<<B, 256, 0, stream>>>(xb, wbt, wct, bbox, bcls, (float*)d_out);
}